// Round 1
// baseline (333.983 us; speedup 1.0000x reference)
//
#include <hip/hip_runtime.h>
#include <math.h>

// Problem constants (fixed by the reference).
#define BB 8
#define CC 256
#define HWP 4096            // H*W
#define NN 1024             // codebook size
#define DD 256              // embedding dim
#define ZQ_SIZE (BB * DD * HWP)   // 8388608 floats

// One block: 64 pixels x all 1024 codes. 256 threads.
// Thread (tx,ty), tx=tid&15 -> 4 pixels, ty=tid>>4 -> 8 codes per n-chunk.
// K-loop: n-chunks of 128 codes, c-chunks of 64 channels staged in LDS.
__global__ __launch_bounds__(256) void argmax_quant_kernel(
    const float* __restrict__ z,      // [B, C, H*W]
    const float* __restrict__ w,      // [N, C]
    const float* __restrict__ bias,   // [N]
    const float* __restrict__ embed,  // [N, D]
    float* __restrict__ out)          // [z_q | diff | ind] flat float32
{
    __shared__ __align__(16) char smem[66304];
    float (*zt)[64]    = (float (*)[64])smem;            // 64c x 64p, 16 KB
    float (*wt)[132]   = (float (*)[132])(smem + 16384); // 64c x 128n (pad 132), 33 KB
    float* redv        = (float*)smem;                   // reduce scratch (reuse)
    int*   redi        = (int*)(smem + 4096);
    int*   indsh       = (int*)(smem + 65792);           // 64 ints
    float (*tile)[257] = (float (*)[257])smem;           // 64p x 256d (pad 257), 64.25 KB

    const int tid = threadIdx.x;
    const int tx  = tid & 15;
    const int ty  = tid >> 4;
    const int b   = blockIdx.x >> 6;          // 64 blocks per batch image
    const int p0  = (blockIdx.x & 63) << 6;   // pixel offset within image

    const float* zb = z + (size_t)b * CC * HWP + p0;

    float bestv[4];
    int   besti[4];
#pragma unroll
    for (int i = 0; i < 4; ++i) { bestv[i] = -INFINITY; besti[i] = 0; }

    for (int nc = 0; nc < NN / 128; ++nc) {
        const int n0 = nc * 128;
        float acc[32];
#pragma unroll
        for (int i = 0; i < 32; ++i) acc[i] = 0.f;

        for (int cc = 0; cc < CC / 64; ++cc) {
            const int c0 = cc * 64;
            __syncthreads();   // previous iteration's readers done
            // Stage z tile: zt[c][p], global reads coalesced along p.
            {
                const int p4 = tid & 15, cl = tid >> 4;
#pragma unroll
                for (int it = 0; it < 4; ++it) {
                    const int c = it * 16 + cl;
                    const float4 v = *(const float4*)(zb + (size_t)(c0 + c) * HWP + p4 * 4);
                    *(float4*)&zt[c][p4 * 4] = v;
                }
            }
            // Stage w tile transposed: wt[c][n], global reads coalesced along c.
            {
                const int c4 = tid & 15, nl = tid >> 4;
#pragma unroll
                for (int it = 0; it < 8; ++it) {
                    const int n = it * 16 + nl;
                    const float4 v = *(const float4*)(w + (size_t)(n0 + n) * CC + c0 + c4 * 4);
                    wt[c4 * 4 + 0][n] = v.x;
                    wt[c4 * 4 + 1][n] = v.y;
                    wt[c4 * 4 + 2][n] = v.z;
                    wt[c4 * 4 + 3][n] = v.w;
                }
            }
            __syncthreads();
            // FMA core: 4 pixels x 8 codes per thread, float4 LDS reads.
#pragma unroll 8
            for (int c = 0; c < 64; ++c) {
                const float4 zv = *(const float4*)&zt[c][tx * 4];
                const float4 w0 = *(const float4*)&wt[c][ty * 8];
                const float4 w1 = *(const float4*)&wt[c][ty * 8 + 4];
                const float zz[4] = {zv.x, zv.y, zv.z, zv.w};
                const float ww[8] = {w0.x, w0.y, w0.z, w0.w, w1.x, w1.y, w1.z, w1.w};
#pragma unroll
                for (int j = 0; j < 8; ++j)
#pragma unroll
                    for (int pi = 0; pi < 4; ++pi)
                        acc[j * 4 + pi] = fmaf(ww[j], zz[pi], acc[j * 4 + pi]);
            }
        }
        // Bias + running argmax (strict > keeps first/lowest index).
        const float4 pb0 = *(const float4*)(bias + n0 + ty * 8);
        const float4 pb1 = *(const float4*)(bias + n0 + ty * 8 + 4);
        const float pb[8] = {pb0.x, pb0.y, pb0.z, pb0.w, pb1.x, pb1.y, pb1.z, pb1.w};
#pragma unroll
        for (int j = 0; j < 8; ++j) {
            const int n = n0 + ty * 8 + j;
#pragma unroll
            for (int pi = 0; pi < 4; ++pi) {
                const float v = acc[j * 4 + pi] + pb[j];
                if (v > bestv[pi]) { bestv[pi] = v; besti[pi] = n; }
            }
        }
    }

    // Cross-thread argmax reduce: 16 candidates (ty) per pixel.
    __syncthreads();
#pragma unroll
    for (int pi = 0; pi < 4; ++pi) {
        const int p = tx * 4 + pi;
        redv[p * 16 + ty] = bestv[pi];
        redi[p * 16 + ty] = besti[pi];
    }
    __syncthreads();
    if (tid < 64) {
        const int p = tid;
        float bv = redv[p * 16];
        int   bi = redi[p * 16];
#pragma unroll
        for (int t = 1; t < 16; ++t) {
            const float v  = redv[p * 16 + t];
            const int   i2 = redi[p * 16 + t];
            if (v > bv || (v == bv && i2 < bi)) { bv = v; bi = i2; }
        }
        indsh[p] = bi;
        // ind output as float32 (exact for 0..1023)
        out[ZQ_SIZE + 1 + b * HWP + p0 + p] = (float)bi;
    }
    if (blockIdx.x == 0 && tid == 0) out[ZQ_SIZE] = 0.0f;  // diff
    __syncthreads();

    // Gather epilogue: embed rows -> LDS tile (coalesced reads),
    // then [b,d,h,w] writes (coalesced along pixels).
    {
        const int lane = tid & 63, wv = tid >> 6;
        for (int it = 0; it < 16; ++it) {
            const int p   = it * 4 + wv;
            const int row = indsh[p];
            const float4 e = *(const float4*)(embed + (size_t)row * DD + lane * 4);
            tile[p][lane * 4 + 0] = e.x;
            tile[p][lane * 4 + 1] = e.y;
            tile[p][lane * 4 + 2] = e.z;
            tile[p][lane * 4 + 3] = e.w;
        }
        __syncthreads();
        float* outz = out + (size_t)b * DD * HWP + p0;
        for (int dd = 0; dd < 64; ++dd) {
            const int d = dd * 4 + wv;
            outz[(size_t)d * HWP + lane] = tile[lane][d];
        }
    }
}

extern "C" void kernel_launch(void* const* d_in, const int* in_sizes, int n_in,
                              void* d_out, int out_size, void* d_ws, size_t ws_size,
                              hipStream_t stream) {
    const float* z     = (const float*)d_in[0];
    const float* w     = (const float*)d_in[1];
    const float* bias  = (const float*)d_in[2];
    const float* embed = (const float*)d_in[3];
    float* out = (float*)d_out;
    hipLaunchKernelGGL(argmax_quant_kernel, dim3(512), dim3(256), 0, stream,
                       z, w, bias, embed, out);
}